// Round 1
// baseline (588.466 us; speedup 1.0000x reference)
//
#include <hip/hip_runtime.h>
#include <hip/hip_bf16.h>

// Shapes: B=16, A=32, T=64, N=8, H=256, E=8, D=32, F=128
// Tokens M = B*A*T*N = 262144. Attention collapses (softmax over S=1 is 1.0):
//   attn_out[b,:,h] = sum_ed v[b,ed]*Wo[ed,h] + bo[h]  (per-batch vector)
//   out = LN2( relu(LN1(x+av)@W1+b1)@W2 + b2 + LN1(x+av) ), attn_score = 1.0

typedef __attribute__((ext_vector_type(4))) float f32x4;
typedef __attribute__((ext_vector_type(8))) short s16x8;

#define TILE 32
#define LDX 260   // fp32 LDS stride for x1 (pad 256+4 -> 2-way-free banks)
#define LDF 136   // bf16 LDS stride for ff (pad 128+8)
#define LN_EPS 1e-6f

__device__ __forceinline__ short f2bs(float f) {
  // fp32 -> bf16 bits, round-to-nearest-even (finite inputs only)
  unsigned int u = __builtin_bit_cast(unsigned int, f);
  unsigned int r = (u + 0x7FFFu + ((u >> 16) & 1u)) >> 16;
  return (short)r;
}

// ---------------- Precompute: attn_vec[b][h] (16 x 256) ----------------
__global__ void attn_vec_kernel(const float* __restrict__ scene,
                                const float* __restrict__ Wv, const float* __restrict__ bv,
                                const float* __restrict__ Wo, const float* __restrict__ bo,
                                float* __restrict__ attn_vec) {
  __shared__ float sc[256];
  __shared__ float vv[256];
  const int b = blockIdx.x, t = threadIdx.x;
  sc[t] = scene[b * 256 + t];
  __syncthreads();
  float acc = bv[t];                       // t indexes ed = e*32+d
  #pragma unroll 4
  for (int h = 0; h < 256; ++h) acc += sc[h] * Wv[h * 256 + t];
  vv[t] = acc;
  __syncthreads();
  float o = bo[t];                         // t indexes h
  #pragma unroll 4
  for (int ed = 0; ed < 256; ++ed) o += vv[ed] * Wo[ed * 256 + t];
  attn_vec[b * 256 + t] = o;
}

// ---------------- Precompute: pack W1/W2 into MFMA B-fragment order ----------------
// W1p[((ks*8+nt)*64 + l)*8 + j]  = bf16( W1[(ks*32 + (l>>4)*8 + j)*128 + nt*16 + (l&15)] )
// W2p[((ks*16+nt)*64 + l)*8 + j] = bf16( W2[(ks*32 + (l>>4)*8 + j)*256 + nt*16 + (l&15)] )
__global__ void pack_kernel(const float* __restrict__ W1, const float* __restrict__ W2,
                            unsigned short* __restrict__ W1p, unsigned short* __restrict__ W2p) {
  const int tid = blockIdx.x * 256 + threadIdx.x;   // 0..65535
  const int i = tid & 32767;
  const int j = i & 7, l = (i >> 3) & 63, g = i >> 9;
  const int krow = (l >> 4) * 8 + j, c = l & 15;
  if (tid < 32768) {
    const int ks = g >> 3, nt = g & 7;
    W1p[i] = (unsigned short)f2bs(W1[(ks * 32 + krow) * 128 + nt * 16 + c]);
  } else {
    const int ks = g >> 4, nt = g & 15;
    W2p[i] = (unsigned short)f2bs(W2[(ks * 32 + krow) * 256 + nt * 16 + c]);
  }
}

// ---------------- attn_score = 1.0 fill ----------------
__global__ void fill_ones_kernel(f32x4* __restrict__ p) {
  const int i = blockIdx.x * 256 + threadIdx.x;   // 524288 float4s = 2097152 floats
  p[i] = (f32x4){1.f, 1.f, 1.f, 1.f};
}

// ---------------- Fused main kernel: 32 tokens per block ----------------
__launch_bounds__(256)
__global__ void main_kernel(const float* __restrict__ hidden,
                            const float* __restrict__ attn_vec,
                            const float* __restrict__ ln1g, const float* __restrict__ ln1b,
                            const unsigned short* __restrict__ W1p, const float* __restrict__ b1,
                            const unsigned short* __restrict__ W2p, const float* __restrict__ b2,
                            const float* __restrict__ ln2g, const float* __restrict__ ln2b,
                            float* __restrict__ out) {
  __shared__ float xs[TILE * LDX];            // x1 fp32 (residual + GEMM1 A), later out staging
  __shared__ unsigned short ffs[TILE * LDF];  // ff bf16 (GEMM2 A)
  __shared__ float red[TILE * 4 * 2];         // per-row per-wave (sum, sumsq)
  __shared__ float murs[TILE * 2];            // per-row (mu, rs)

  const int tid  = threadIdx.x;
  const int lane = tid & 63;
  const int w    = tid >> 6;        // wave 0..3
  const int l15  = lane & 15, l4 = lane >> 4;
  const long base_tok = (long)blockIdx.x * TILE;
  const float* hp = hidden + base_tok * 256;
  float* outp = out + base_tok * 256;

  // --- prefetch GEMM1 B fragments: wave w owns ff cols [w*32, w*32+32) ---
  s16x8 b1f[8][2];
  #pragma unroll
  for (int ks = 0; ks < 8; ++ks)
    #pragma unroll
    for (int ntl = 0; ntl < 2; ++ntl)
      b1f[ks][ntl] = *(const s16x8*)(W1p + (((ks * 8) + (w * 2 + ntl)) * 64 + lane) * 8);

  // --- per-lane column constants ---
  float b1c[2];
  #pragma unroll
  for (int ntl = 0; ntl < 2; ++ntl) b1c[ntl] = b1[w * 32 + ntl * 16 + l15];
  float b2c[4], g2c[4], be2c[4];
  #pragma unroll
  for (int ntl = 0; ntl < 4; ++ntl) {
    const int c = w * 64 + ntl * 16 + l15;
    b2c[ntl] = b2[c]; g2c[ntl] = ln2g[c]; be2c[ntl] = ln2b[c];
  }

  // ================= Phase 1: load + LN1 =================
  // thread holds tokens {i*4 + w}, channels [ (tid&63)*4 .. +4 )
  const int csub = tid & 63;
  const int bidx = (int)(base_tok >> 14);     // token/16384 = batch (tile-aligned)
  const f32x4 av  = *(const f32x4*)(attn_vec + bidx * 256 + csub * 4);
  const f32x4 g1  = *(const f32x4*)(ln1g + csub * 4);
  const f32x4 be1 = *(const f32x4*)(ln1b + csub * 4);

  f32x4 xv[8];
  #pragma unroll
  for (int i = 0; i < 8; ++i) {
    const int token = i * 4 + w;
    xv[i] = *(const f32x4*)(hp + token * 256 + csub * 4) + av;
  }
  #pragma unroll
  for (int i = 0; i < 8; ++i) {
    float s = xv[i][0] + xv[i][1] + xv[i][2] + xv[i][3];
    float q = xv[i][0]*xv[i][0] + xv[i][1]*xv[i][1] + xv[i][2]*xv[i][2] + xv[i][3]*xv[i][3];
    #pragma unroll
    for (int d = 1; d < 64; d <<= 1) { s += __shfl_xor(s, d); q += __shfl_xor(q, d); }
    const float mu = s * (1.f / 256.f);
    const float rs = rsqrtf(q * (1.f / 256.f) - mu * mu + LN_EPS);
    const f32x4 x1 = (xv[i] - mu) * rs * g1 + be1;
    const int token = i * 4 + w;
    *(f32x4*)&xs[token * LDX + csub * 4] = x1;
  }
  __syncthreads();

  // ================= Phase 2: GEMM1 (x1 @ W1), relu, -> ffs =================
  f32x4 acc1[2][2] = {};
  #pragma unroll
  for (int ks = 0; ks < 8; ++ks) {
    #pragma unroll
    for (int m = 0; m < 2; ++m) {
      const float* ap = &xs[(m * 16 + l15) * LDX + ks * 32 + l4 * 8];
      const f32x4 a0 = *(const f32x4*)ap;
      const f32x4 a1 = *(const f32x4*)(ap + 4);
      s16x8 af;
      af[0]=f2bs(a0[0]); af[1]=f2bs(a0[1]); af[2]=f2bs(a0[2]); af[3]=f2bs(a0[3]);
      af[4]=f2bs(a1[0]); af[5]=f2bs(a1[1]); af[6]=f2bs(a1[2]); af[7]=f2bs(a1[3]);
      #pragma unroll
      for (int ntl = 0; ntl < 2; ++ntl)
        acc1[m][ntl] = __builtin_amdgcn_mfma_f32_16x16x32_bf16(af, b1f[ks][ntl], acc1[m][ntl], 0, 0, 0);
    }
  }
  #pragma unroll
  for (int m = 0; m < 2; ++m)
    #pragma unroll
    for (int ntl = 0; ntl < 2; ++ntl) {
      const int col = w * 32 + ntl * 16 + l15;
      #pragma unroll
      for (int r = 0; r < 4; ++r) {
        const float z = fmaxf(acc1[m][ntl][r] + b1c[ntl], 0.f);
        ffs[(m * 16 + l4 * 4 + r) * LDF + col] = (unsigned short)f2bs(z);
      }
    }

  // prefetch GEMM2 B fragments: wave w owns out cols [w*64, w*64+64)
  s16x8 b2f[4][4];
  #pragma unroll
  for (int ks = 0; ks < 4; ++ks)
    #pragma unroll
    for (int ntl = 0; ntl < 4; ++ntl)
      b2f[ks][ntl] = *(const s16x8*)(W2p + (((ks * 16) + (w * 4 + ntl)) * 64 + lane) * 8);
  __syncthreads();

  // ================= Phase 3: GEMM2 (ff @ W2) =================
  f32x4 acc2[2][4] = {};
  #pragma unroll
  for (int ks = 0; ks < 4; ++ks) {
    #pragma unroll
    for (int m = 0; m < 2; ++m) {
      const s16x8 af = *(const s16x8*)&ffs[(m * 16 + l15) * LDF + ks * 32 + l4 * 8];
      #pragma unroll
      for (int ntl = 0; ntl < 4; ++ntl)
        acc2[m][ntl] = __builtin_amdgcn_mfma_f32_16x16x32_bf16(af, b2f[ks][ntl], acc2[m][ntl], 0, 0, 0);
    }
  }

  // ================= Phase 4: z = y + b2 + x1, LN2, store =================
  #pragma unroll
  for (int m = 0; m < 2; ++m)
    #pragma unroll
    for (int ntl = 0; ntl < 4; ++ntl) {
      const int col = w * 64 + ntl * 16 + l15;
      #pragma unroll
      for (int r = 0; r < 4; ++r) {
        const int row = m * 16 + l4 * 4 + r;
        acc2[m][ntl][r] += b2c[ntl] + xs[row * LDX + col];   // stash z in acc regs
      }
    }
  #pragma unroll
  for (int m = 0; m < 2; ++m)
    #pragma unroll
    for (int r = 0; r < 4; ++r) {
      float s = 0.f, q = 0.f;
      #pragma unroll
      for (int ntl = 0; ntl < 4; ++ntl) { const float z = acc2[m][ntl][r]; s += z; q += z * z; }
      #pragma unroll
      for (int d = 1; d < 16; d <<= 1) { s += __shfl_xor(s, d); q += __shfl_xor(q, d); }
      if (l15 == 0) {
        const int row = m * 16 + l4 * 4 + r;
        red[(row * 4 + w) * 2 + 0] = s;
        red[(row * 4 + w) * 2 + 1] = q;
      }
    }
  __syncthreads();
  if (tid < TILE) {
    float s = 0.f, q = 0.f;
    #pragma unroll
    for (int ww = 0; ww < 4; ++ww) { s += red[(tid * 4 + ww) * 2]; q += red[(tid * 4 + ww) * 2 + 1]; }
    const float mu = s * (1.f / 256.f);
    murs[tid * 2 + 0] = mu;
    murs[tid * 2 + 1] = rsqrtf(q * (1.f / 256.f) - mu * mu + LN_EPS);
  }
  __syncthreads();
  #pragma unroll
  for (int m = 0; m < 2; ++m)
    #pragma unroll
    for (int r = 0; r < 4; ++r) {
      const int row = m * 16 + l4 * 4 + r;
      const float mu = murs[row * 2], rs = murs[row * 2 + 1];
      #pragma unroll
      for (int ntl = 0; ntl < 4; ++ntl) {
        const int col = w * 64 + ntl * 16 + l15;
        xs[row * LDX + col] = (acc2[m][ntl][r] - mu) * rs * g2c[ntl] + be2c[ntl];
      }
    }
  __syncthreads();
  #pragma unroll
  for (int i = 0; i < 8; ++i) {
    const int token = i * 4 + w;
    *(f32x4*)(outp + token * 256 + csub * 4) = *(const f32x4*)&xs[token * LDX + csub * 4];
  }
}

// ---------------- launcher ----------------
extern "C" void kernel_launch(void* const* d_in, const int* in_sizes, int n_in,
                              void* d_out, int out_size, void* d_ws, size_t ws_size,
                              hipStream_t stream) {
  const float* hidden = (const float*)d_in[0];
  const float* scene  = (const float*)d_in[1];
  // d_in[2..5] = Wq, bq, Wk, bk : dead (softmax over S=1 is identically 1)
  const float* Wv   = (const float*)d_in[6];
  const float* bv   = (const float*)d_in[7];
  const float* Wo   = (const float*)d_in[8];
  const float* bo   = (const float*)d_in[9];
  const float* ln1g = (const float*)d_in[10];
  const float* ln1b = (const float*)d_in[11];
  const float* W1   = (const float*)d_in[12];
  const float* b1   = (const float*)d_in[13];
  const float* W2   = (const float*)d_in[14];
  const float* b2   = (const float*)d_in[15];
  const float* ln2g = (const float*)d_in[16];
  const float* ln2b = (const float*)d_in[17];
  float* out = (float*)d_out;

  float* attn_vec = (float*)d_ws;                                   // 16*256 fp32
  unsigned short* W1p = (unsigned short*)((char*)d_ws + 16384);     // 32768 bf16
  unsigned short* W2p = (unsigned short*)((char*)d_ws + 16384 + 65536);

  attn_vec_kernel<<<16, 256, 0, stream>>>(scene, Wv, bv, Wo, bo, attn_vec);
  pack_kernel<<<256, 256, 0, stream>>>(W1, W2, W1p, W2p);
  fill_ones_kernel<<<2048, 256, 0, stream>>>((f32x4*)(out + 67108864));
  main_kernel<<<8192, 256, 0, stream>>>(hidden, attn_vec, ln1g, ln1b,
                                        W1p, b1, W2p, b2, ln2g, ln2b, out);
}

// Round 3
// 554.124 us; speedup vs baseline: 1.0620x; 1.0620x over previous
//
#include <hip/hip_runtime.h>
#include <hip/hip_bf16.h>

// Shapes: B=16, A=32, T=64, N=8, H=256, E=8, D=32, F=128
// Attention collapses (softmax over S=1 is identically 1.0):
//   attn_out[b,:,h] = sum_ed v[b,ed]*Wo[ed,h] + bo[h]  (per-batch vector)
//   out = LN2( relu(LN1(x+av)@W1+b1)@W2 + b2 + LN1(x+av) ), attn_score = 1.0

typedef __attribute__((ext_vector_type(4))) float f32x4;
typedef __attribute__((ext_vector_type(8))) short s16x8;
typedef __attribute__((ext_vector_type(4))) short s16x4;

#define TILE 32
#define LDXS 264   // bf16 LDS stride for x1 (256+8 shorts; 528B rows -> 2-way banks, free)
#define LDF  136   // bf16 LDS stride for ff (128+8)
#define LDR  12    // f32 stride for per-row wave partials
#define LN_EPS 1e-6f

__device__ __forceinline__ short f2bs(float f) {
  // fp32 -> bf16 bits, round-to-nearest-even (finite inputs only)
  unsigned int u = __builtin_bit_cast(unsigned int, f);
  unsigned int r = (u + 0x7FFFu + ((u >> 16) & 1u)) >> 16;
  return (short)r;
}
__device__ __forceinline__ float bs2f(unsigned short s) {
  unsigned int u = ((unsigned int)s) << 16;
  return __builtin_bit_cast(float, u);
}

// ---------------- Fused prep: attn_vec (16 blk) + weight pack (256 blk) + score fill (2048 blk) ----------------
__global__ void prep_kernel(const float* __restrict__ scene,
                            const float* __restrict__ Wv, const float* __restrict__ bv,
                            const float* __restrict__ Wo, const float* __restrict__ bo,
                            const float* __restrict__ W1, const float* __restrict__ W2,
                            float* __restrict__ attn_vec,
                            unsigned short* __restrict__ W1p, unsigned short* __restrict__ W2p,
                            f32x4* __restrict__ score) {
  __shared__ float sc[256];
  __shared__ float vv[256];
  const int bid = blockIdx.x, t = threadIdx.x;
  if (bid < 16) {
    const int b = bid;
    sc[t] = scene[b * 256 + t];
    __syncthreads();
    float acc = bv[t];                       // t indexes ed = e*32+d
    #pragma unroll 8
    for (int h = 0; h < 256; ++h) acc += sc[h] * Wv[h * 256 + t];
    vv[t] = acc;
    __syncthreads();
    float o = bo[t];                         // t indexes h
    #pragma unroll 8
    for (int ed = 0; ed < 256; ++ed) o += vv[ed] * Wo[ed * 256 + t];
    attn_vec[b * 256 + t] = o;
  } else if (bid < 272) {
    // pack W1/W2 into MFMA B-fragment order (same layout as validated R1 kernel):
    // W1p[((ks*8+nt)*64 + l)*8 + j]  = bf16( W1[(ks*32 + (l>>4)*8 + j)*128 + nt*16 + (l&15)] )
    // W2p[((ks*16+nt)*64 + l)*8 + j] = bf16( W2[(ks*32 + (l>>4)*8 + j)*256 + nt*16 + (l&15)] )
    const int tid = (bid - 16) * 256 + t;    // 0..65535
    const int i = tid & 32767;
    const int j = i & 7, l = (i >> 3) & 63, g = i >> 9;
    const int krow = (l >> 4) * 8 + j, c = l & 15;
    if (tid < 32768) {
      const int ks = g >> 3, nt = g & 7;
      W1p[i] = (unsigned short)f2bs(W1[(ks * 32 + krow) * 128 + nt * 16 + c]);
    } else {
      const int ks = g >> 4, nt = g & 15;
      W2p[i] = (unsigned short)f2bs(W2[(ks * 32 + krow) * 256 + nt * 16 + c]);
    }
  } else {
    const int i = (bid - 272) * 256 + t;     // 524288 f32x4 = 2097152 floats
    score[i] = (f32x4){1.f, 1.f, 1.f, 1.f};
  }
}

// ---------------- Fused main kernel: 32 tokens per block ----------------
__launch_bounds__(256, 5)
__global__ void main_kernel(const float* __restrict__ hidden,
                            const float* __restrict__ attn_vec,
                            const float* __restrict__ ln1g, const float* __restrict__ ln1b,
                            const unsigned short* __restrict__ W1p, const float* __restrict__ b1,
                            const unsigned short* __restrict__ W2p, const float* __restrict__ b2,
                            const float* __restrict__ ln2g, const float* __restrict__ ln2b,
                            float* __restrict__ out) {
  __shared__ unsigned short xs[TILE * LDXS];   // x1 bf16 (GEMM1 A + residual)   16896 B
  __shared__ unsigned short ffs[TILE * LDF];   // ff bf16 (GEMM2 A)               8704 B
  __shared__ float red[TILE * LDR];            // per-row per-wave (s,q)          1536 B

  const int tid  = threadIdx.x;
  const int lane = tid & 63;
  const int w    = tid >> 6;        // wave 0..3
  const int l15  = lane & 15, l4 = lane >> 4;
  const long base_tok = (long)blockIdx.x * TILE;
  const float* hp = hidden + base_tok * 256;
  float* outp = out + base_tok * 256;

  // --- issue all phase-1 global loads up front (8 token-chunks in flight) ---
  const int bidx = (int)(base_tok >> 14);      // token/16384 = batch (tile-aligned)
  const f32x4 av  = *(const f32x4*)(attn_vec + bidx * 256 + lane * 4);
  const f32x4 g1  = *(const f32x4*)(ln1g + lane * 4);
  const f32x4 be1 = *(const f32x4*)(ln1b + lane * 4);
  f32x4 xv[8];
  #pragma unroll
  for (int i = 0; i < 8; ++i)
    xv[i] = *(const f32x4*)(hp + (i * 4 + w) * 256 + lane * 4);

  // --- prefetch GEMM1 B fragments, first half (ks 0..3); wave w owns ff cols [w*32,+32) ---
  s16x8 b1f[4][2];
  #pragma unroll
  for (int ks = 0; ks < 4; ++ks)
    #pragma unroll
    for (int ntl = 0; ntl < 2; ++ntl)
      b1f[ks][ntl] = *(const s16x8*)(W1p + (((ks * 8) + (w * 2 + ntl)) * 64 + lane) * 8);

  // --- per-lane column constants ---
  float b1c[2];
  #pragma unroll
  for (int ntl = 0; ntl < 2; ++ntl) b1c[ntl] = b1[w * 32 + ntl * 16 + l15];
  float b2c[4], g2c[4], be2c[4];
  #pragma unroll
  for (int ntl = 0; ntl < 4; ++ntl) {
    const int c = w * 64 + ntl * 16 + l15;
    b2c[ntl] = b2[c]; g2c[ntl] = ln2g[c]; be2c[ntl] = ln2b[c];
  }

  // ================= Phase 1: LN1 -> xs (bf16) =================
  #pragma unroll
  for (int i = 0; i < 8; ++i) {
    const int token = i * 4 + w;               // whole wave works one token
    const f32x4 x = xv[i] + av;
    float s = x[0] + x[1] + x[2] + x[3];
    float q = x[0]*x[0] + x[1]*x[1] + x[2]*x[2] + x[3]*x[3];
    #pragma unroll
    for (int d = 1; d < 64; d <<= 1) { s += __shfl_xor(s, d); q += __shfl_xor(q, d); }
    const float mu = s * (1.f / 256.f);
    const float rs = rsqrtf(q * (1.f / 256.f) - mu * mu + LN_EPS);
    const f32x4 x1 = (x - mu) * rs * g1 + be1;
    s16x4 xb;
    xb[0] = f2bs(x1[0]); xb[1] = f2bs(x1[1]); xb[2] = f2bs(x1[2]); xb[3] = f2bs(x1[3]);
    *(s16x4*)&xs[token * LDXS + lane * 4] = xb;
  }
  __syncthreads();   // B1: xs ready

  // ================= Phase 2: GEMM1 (x1 @ W1) =================
  f32x4 acc1[2][2] = {};
  #pragma unroll
  for (int ks = 0; ks < 4; ++ks)
    #pragma unroll
    for (int m = 0; m < 2; ++m) {
      const s16x8 af = *(const s16x8*)&xs[(m * 16 + l15) * LDXS + ks * 32 + l4 * 8];
      #pragma unroll
      for (int ntl = 0; ntl < 2; ++ntl)
        acc1[m][ntl] = __builtin_amdgcn_mfma_f32_16x16x32_bf16(af, b1f[ks][ntl], acc1[m][ntl], 0, 0, 0);
    }
  #pragma unroll
  for (int ks = 0; ks < 4; ++ks)      // second-half B fragments (ks 4..7)
    #pragma unroll
    for (int ntl = 0; ntl < 2; ++ntl)
      b1f[ks][ntl] = *(const s16x8*)(W1p + ((((ks + 4) * 8) + (w * 2 + ntl)) * 64 + lane) * 8);
  #pragma unroll
  for (int ks = 0; ks < 4; ++ks)
    #pragma unroll
    for (int m = 0; m < 2; ++m) {
      const s16x8 af = *(const s16x8*)&xs[(m * 16 + l15) * LDXS + (ks + 4) * 32 + l4 * 8];
      #pragma unroll
      for (int ntl = 0; ntl < 2; ++ntl)
        acc1[m][ntl] = __builtin_amdgcn_mfma_f32_16x16x32_bf16(af, b1f[ks][ntl], acc1[m][ntl], 0, 0, 0);
    }

  // relu + bias -> ffs (bf16)
  #pragma unroll
  for (int m = 0; m < 2; ++m)
    #pragma unroll
    for (int ntl = 0; ntl < 2; ++ntl) {
      const int col = w * 32 + ntl * 16 + l15;
      #pragma unroll
      for (int r = 0; r < 4; ++r) {
        const float z = fmaxf(acc1[m][ntl][r] + b1c[ntl], 0.f);
        ffs[(m * 16 + l4 * 4 + r) * LDF + col] = (unsigned short)f2bs(z);
      }
    }

  // prefetch GEMM2 B fragments, first half (ks 0..1); wave w owns out cols [w*64,+64)
  s16x8 b2f[2][4];
  #pragma unroll
  for (int ks = 0; ks < 2; ++ks)
    #pragma unroll
    for (int ntl = 0; ntl < 4; ++ntl)
      b2f[ks][ntl] = *(const s16x8*)(W2p + (((ks * 16) + (w * 4 + ntl)) * 64 + lane) * 8);
  __syncthreads();   // B2: ffs ready

  // ================= Phase 3: GEMM2 (ff @ W2) =================
  f32x4 acc2[2][4] = {};
  #pragma unroll
  for (int ks = 0; ks < 2; ++ks)
    #pragma unroll
    for (int m = 0; m < 2; ++m) {
      const s16x8 af = *(const s16x8*)&ffs[(m * 16 + l15) * LDF + ks * 32 + l4 * 8];
      #pragma unroll
      for (int ntl = 0; ntl < 4; ++ntl)
        acc2[m][ntl] = __builtin_amdgcn_mfma_f32_16x16x32_bf16(af, b2f[ks][ntl], acc2[m][ntl], 0, 0, 0);
    }
  #pragma unroll
  for (int ks = 0; ks < 2; ++ks)      // second-half B fragments (ks 2..3)
    #pragma unroll
    for (int ntl = 0; ntl < 4; ++ntl)
      b2f[ks][ntl] = *(const s16x8*)(W2p + ((((ks + 2) * 16) + (w * 4 + ntl)) * 64 + lane) * 8);
  #pragma unroll
  for (int ks = 0; ks < 2; ++ks)
    #pragma unroll
    for (int m = 0; m < 2; ++m) {
      const s16x8 af = *(const s16x8*)&ffs[(m * 16 + l15) * LDF + (ks + 2) * 32 + l4 * 8];
      #pragma unroll
      for (int ntl = 0; ntl < 4; ++ntl)
        acc2[m][ntl] = __builtin_amdgcn_mfma_f32_16x16x32_bf16(af, b2f[ks][ntl], acc2[m][ntl], 0, 0, 0);
    }

  // ================= Phase 4: z = y + b2 + x1, LN2, direct store =================
  #pragma unroll
  for (int m = 0; m < 2; ++m)
    #pragma unroll
    for (int ntl = 0; ntl < 4; ++ntl) {
      const int col = w * 64 + ntl * 16 + l15;
      #pragma unroll
      for (int r = 0; r < 4; ++r) {
        const int row = m * 16 + l4 * 4 + r;
        acc2[m][ntl][r] += b2c[ntl] + bs2f(xs[row * LDXS + col]);   // z kept in regs
      }
    }
  // per-row wave partials (sum over this wave's 64 cols)
  #pragma unroll
  for (int m = 0; m < 2; ++m)
    #pragma unroll
    for (int r = 0; r < 4; ++r) {
      float s = 0.f, q = 0.f;
      #pragma unroll
      for (int ntl = 0; ntl < 4; ++ntl) { const float z = acc2[m][ntl][r]; s += z; q += z * z; }
      #pragma unroll
      for (int d = 1; d < 16; d <<= 1) { s += __shfl_xor(s, d); q += __shfl_xor(q, d); }
      if (l15 == 0) {
        const int row = m * 16 + l4 * 4 + r;
        red[row * LDR + w * 2 + 0] = s;
        red[row * LDR + w * 2 + 1] = q;
      }
    }
  __syncthreads();   // B3: partials ready
  #pragma unroll
  for (int m = 0; m < 2; ++m)
    #pragma unroll
    for (int r = 0; r < 4; ++r) {
      const int row = m * 16 + l4 * 4 + r;
      const f32x4 a = *(const f32x4*)&red[row * LDR];       // (s0,q0,s1,q1)
      const f32x4 b = *(const f32x4*)&red[row * LDR + 4];   // (s2,q2,s3,q3)
      const float s = a[0] + a[2] + b[0] + b[2];
      const float q = a[1] + a[3] + b[1] + b[3];
      const float mu = s * (1.f / 256.f);
      const float rs = rsqrtf(q * (1.f / 256.f) - mu * mu + LN_EPS);
      #pragma unroll
      for (int ntl = 0; ntl < 4; ++ntl) {
        const int col = w * 64 + ntl * 16 + l15;
        outp[row * 256 + col] = (acc2[m][ntl][r] - mu) * rs * g2c[ntl] + be2c[ntl];
      }
    }
}

// ---------------- launcher ----------------
extern "C" void kernel_launch(void* const* d_in, const int* in_sizes, int n_in,
                              void* d_out, int out_size, void* d_ws, size_t ws_size,
                              hipStream_t stream) {
  const float* hidden = (const float*)d_in[0];
  const float* scene  = (const float*)d_in[1];
  // d_in[2..5] = Wq, bq, Wk, bk : dead (softmax over S=1 is identically 1)
  const float* Wv   = (const float*)d_in[6];
  const float* bv   = (const float*)d_in[7];
  const float* Wo   = (const float*)d_in[8];
  const float* bo   = (const float*)d_in[9];
  const float* ln1g = (const float*)d_in[10];
  const float* ln1b = (const float*)d_in[11];
  const float* W1   = (const float*)d_in[12];
  const float* b1   = (const float*)d_in[13];
  const float* W2   = (const float*)d_in[14];
  const float* b2   = (const float*)d_in[15];
  const float* ln2g = (const float*)d_in[16];
  const float* ln2b = (const float*)d_in[17];
  float* out = (float*)d_out;

  float* attn_vec = (float*)d_ws;                                   // 16*256 fp32
  unsigned short* W1p = (unsigned short*)((char*)d_ws + 16384);     // 32768 bf16
  unsigned short* W2p = (unsigned short*)((char*)d_ws + 16384 + 65536);

  prep_kernel<<<2320, 256, 0, stream>>>(scene, Wv, bv, Wo, bo, W1, W2,
                                        attn_vec, W1p, W2p,
                                        (f32x4*)(out + 67108864));
  main_kernel<<<8192, 256, 0, stream>>>(hidden, attn_vec, ln1g, ln1b,
                                        W1p, b1, W2p, b2, ln2g, ln2b, out);
}